// Round 8
// baseline (15448.244 us; speedup 1.0000x reference)
//
#include <hip/hip_runtime.h>

typedef __attribute__((ext_vector_type(8))) short bf16x8;
typedef __attribute__((ext_vector_type(4))) float f32x4;
typedef __attribute__((ext_vector_type(4))) unsigned int u32x4;
typedef __attribute__((ext_vector_type(2))) unsigned int u32x2;

#define T_SEQ 2048
#define RING  16
#define NL0   32
#define NL1   32
#define NFC   8
#define SLOT_STRIDE 16
#define SLOT_U32 (32 * 512)           // ring slot: [batch][unit] u32 (tag|bf16)
#define TAGW(t) ((unsigned)((t) + 1) << 16)

// XOR swizzle for 1024B-row-stride LDS tiles
#define HSWZ(o) ((o) ^ ((((o) >> 10) & 7) << 4))

static __device__ __forceinline__ unsigned short f2b(float f) {
  unsigned u = __float_as_uint(f);
  u = (u + 0x7fffu + ((u >> 16) & 1u)) >> 16;
  return (unsigned short)u;
}
static __device__ __forceinline__ float sigm(float x) { return 1.f / (1.f + __expf(-x)); }
static __device__ __forceinline__ float tanh_f(float x) { return 2.f / (1.f + __expf(-2.f * x)) - 1.f; }

// ring loads: sc0 = agent/L2-coherent (fast, XCD-local); sc0 sc1 = LLC (authoritative)
static __device__ __forceinline__ u32x4 ring_load(const void* p, bool via_llc) {
  u32x4 v;
  if (via_llc)
    asm volatile("global_load_dwordx4 %0, %1, off sc0 sc1" : "=v"(v) : "v"(p) : "memory");
  else
    asm volatile("global_load_dwordx4 %0, %1, off sc0" : "=v"(v) : "v"(p) : "memory");
  return v;
}
static __device__ __forceinline__ void llc_store8(void* p, u32x2 v) {
  asm volatile("global_store_dwordx2 %0, %1, off sc0 sc1" :: "v"(p), "v"(v) : "memory");
}
static __device__ __forceinline__ void vmwait() {
  asm volatile("s_waitcnt vmcnt(0)" ::: "memory");
}
static __device__ __forceinline__ int flag_ld(const int* p) {
  return __hip_atomic_load(p, __ATOMIC_RELAXED, __HIP_MEMORY_SCOPE_SYSTEM);
}
static __device__ __forceinline__ void flag_st(int* p, int v) {
  __hip_atomic_store(p, v, __ATOMIC_RELAXED, __HIP_MEMORY_SCOPE_SYSTEM);
}

// rare ring-overwrite guard (wave 0 only): first NC lanes check prog >= need
template <int NC>
static __device__ __forceinline__ void guard_poll(const int* prog, int need) {
  const int lane = threadIdx.x & 63;
  for (;;) {
    int v = 0x7fffffff;
    if (lane < NC) v = flag_ld(prog + lane * SLOT_STRIDE);
    if (__all(v >= need)) break;
  }
}

// ---- tagged-ring staging: load chunks, verify embedded tags, retry stale ----
// A_LLC/B_LLC: 1 = always LLC (cross-XCD source); 0 = sc0-first with sc1 escape
// every 4th round (XCD-local fast path, deadlock-safe under any placement).
template <int TWO, int A_LLC, int B_LLC>
static __device__ void stage_tag(const unsigned* srcA, unsigned tagA, unsigned short* dstA,
                                 const unsigned* srcB, unsigned tagB, unsigned short* dstB,
                                 int tid) {
  constexpr int NCH = TWO ? 32 : 16;
  u32x4 v[NCH];
  unsigned mask = TWO ? 0xffffffffu : 0xffffu;
  int rnd = 0;
  while (mask) {
    const bool esc = ((rnd & 3) == 3);
#pragma unroll
    for (int k = 0; k < NCH; ++k)
      if ((mask >> k) & 1u) {
        const bool llc = (k < 16) ? (A_LLC || esc) : (B_LLC || esc);
        const unsigned* s = (k < 16) ? srcA : srcB;
        v[k] = ring_load((const char*)s + ((size_t)tid + (k & 15) * 256) * 16, llc);
      }
    vmwait();
    unsigned nm = 0;
#pragma unroll
    for (int k = 0; k < NCH; ++k)
      if ((mask >> k) & 1u) {
        unsigned tw = (k < 16) ? tagA : tagB;
        unsigned d = ((v[k].x ^ tw) | (v[k].y ^ tw) | (v[k].z ^ tw) | (v[k].w ^ tw)) & 0xffff0000u;
        if (d == 0) {
          int c = tid + (k & 15) * 256;
          u32x2 p;
          p.x = (v[k].x & 0xffffu) | (v[k].y << 16);
          p.y = (v[k].z & 0xffffu) | (v[k].w << 16);
          int off = (c >> 7) * 1024 + (c & 127) * 8;
          unsigned short* dst = (k < 16) ? dstA : dstB;
          *(u32x2*)((char*)dst + HSWZ(off)) = p;
        } else {
          nm |= 1u << k;
        }
      }
    mask = nm;
    ++rnd;
  }
}

// ---------------- prologue ----------------
__global__ void lstm_prologue(
    const float* __restrict__ x, const float* __restrict__ wih0, const float* __restrict__ whh0,
    const float* __restrict__ wih1, const float* __restrict__ whh1, const float* __restrict__ wfc,
    unsigned short* __restrict__ wl0, unsigned short* __restrict__ wl1,
    unsigned short* __restrict__ wfcp, unsigned short* __restrict__ xb,
    unsigned* __restrict__ h0r, unsigned* __restrict__ h1r,
    int* __restrict__ flags) {
  size_t tid = (size_t)blockIdx.x * blockDim.x + threadIdx.x;
  size_t nthr = (size_t)gridDim.x * blockDim.x;
  for (size_t i = tid; i < (size_t)2048 * 768; i += nthr) {
    int r = (int)(i / 768), k = (int)(i % 768);
    float v = (k < 256) ? wih0[(size_t)r * 256 + k] : whh0[(size_t)r * 512 + (k - 256)];
    wl0[i] = f2b(v);
  }
  for (size_t i = tid; i < (size_t)2048 * 1024; i += nthr) {
    int r = (int)(i >> 10), k = (int)(i & 1023);
    float v = (k < 512) ? wih1[((size_t)r << 9) + k] : whh1[((size_t)r << 9) + (k - 512)];
    wl1[i] = f2b(v);
  }
  for (size_t i = tid; i < 131072; i += nthr) wfcp[i] = f2b(wfc[i]);
  for (size_t i = tid; i < (size_t)16777216; i += nthr) {
    int ii = (int)(i & 255), b = (int)((i >> 8) & 31), t = (int)(i >> 13);
    xb[i] = f2b(x[((size_t)b * 2048 + t) * 256 + ii]);
  }
  for (size_t i = tid; i < (NL1 + NFC) * SLOT_STRIDE; i += nthr) flags[i] = 0;
  // slot for t=-1 (slot RING-1): value 0, tag 0 == TAGW(-1)
  for (size_t i = tid; i < SLOT_U32; i += nthr) {
    h0r[(size_t)(RING - 1) * SLOT_U32 + i] = 0;
    h1r[(size_t)(RING - 1) * SLOT_U32 + i] = 0;
  }
}

// ---------------- LSTM layer body (gate-split waves, tagged rings) ----------------
template <int ISL0>
static __device__ void lstm_path(
    const unsigned short* __restrict__ xb, const unsigned short* __restrict__ wl,
    const float* __restrict__ bias,
    unsigned* __restrict__ h0r, unsigned* __restrict__ h1r,
    int* l1prog, int* fcprog, int wid2,
    unsigned short* hA, unsigned short* xA, float (*gates)[32][18]) {
  const int tid = threadIdx.x;
  const int wave = tid >> 6, lane = tid & 63, l15 = lane & 15, kgrp = lane >> 4;
  const int u0 = wid2 * 16;
  constexpr int K = ISL0 ? 768 : 1024;
  constexpr int NKW = ISL0 ? 24 : 32;
  const unsigned short* wrow = wl + (size_t)(wave * 512 + u0 + l15) * K;

  bf16x8 wf[NKW];
#pragma unroll
  for (int kk = 0; kk < NKW; ++kk) {
    wf[kk] = *(const bf16x8*)(wrow + kk * 32 + kgrp * 8);
    asm volatile("" : "+v"(wf[kk]));
  }

  const int ue = 2 * (tid & 7);
  const int be = tid >> 3;
  const float bi0 = bias[0 * 512 + u0 + ue], bi1 = bias[0 * 512 + u0 + ue + 1];
  const float bf0 = bias[1 * 512 + u0 + ue], bf1 = bias[1 * 512 + u0 + ue + 1];
  const float bg0 = bias[2 * 512 + u0 + ue], bg1 = bias[2 * 512 + u0 + ue + 1];
  const float bo0 = bias[3 * 512 + u0 + ue], bo1 = bias[3 * 512 + u0 + ue + 1];
  float cc0 = 0.f, cc1 = 0.f;
  unsigned* myring = ISL0 ? h0r : h1r;

  for (int t = 0; t < T_SEQ; ++t) {
    // amortized ring-overwrite guards (consumer progress, every 4 steps)
    if ((t & 3) == 0 && t >= RING && wave == 0) {
      if (ISL0) guard_poll<NL1>(l1prog, t - 8);   // L1 consumed h0[t-16..]
      else      guard_poll<NFC>(fcprog, t - 8);   // FC consumed h1[t-16..]
    }

    // x fragment prefetch (L0 only; static data)
    bf16x8 xf0[8], xf1[8];
    if (ISL0) {
      const unsigned short* xt = xb + (size_t)t * (32 * 256);
#pragma unroll
      for (int kk = 0; kk < 8; ++kk) {
        xf0[kk] = *(const bf16x8*)(xt + l15 * 256 + kk * 32 + kgrp * 8);
        xf1[kk] = *(const bf16x8*)(xt + (16 + l15) * 256 + kk * 32 + kgrp * 8);
      }
    }

    // ---- tagged staging (detect + load fused; no flags, no producer barrier) ----
    if (ISL0) {
      stage_tag<0, 0, 0>(myring + (size_t)((t - 1) & (RING - 1)) * SLOT_U32, TAGW(t - 1), hA,
                         nullptr, 0, nullptr, tid);
    } else {
      stage_tag<1, 0, 1>(h1r + (size_t)((t - 1) & (RING - 1)) * SLOT_U32, TAGW(t - 1), hA,
                         h0r + (size_t)(t & (RING - 1)) * SLOT_U32, TAGW(t), xA, tid);
    }

    // L0 x-part MFMAs before the barrier (register-only)
    f32x4 acc0 = {0.f, 0.f, 0.f, 0.f}, acc1 = {0.f, 0.f, 0.f, 0.f};
    if (ISL0) {
#pragma unroll
      for (int kk = 0; kk < 8; ++kk) {
        acc0 = __builtin_amdgcn_mfma_f32_16x16x32_bf16(xf0[kk], wf[kk], acc0, 0, 0, 0);
        acc1 = __builtin_amdgcn_mfma_f32_16x16x32_bf16(xf1[kk], wf[kk], acc1, 0, 0, 0);
      }
    }
    __syncthreads();  // stage barrier

    // publish consumed-h0 progress (L1), after all threads staged
    if (!ISL0 && (t & 3) == 3 && tid == 0) flag_st(l1prog + wid2 * SLOT_STRIDE, t + 1);

    if (ISL0) {
#pragma unroll
      for (int kk = 0; kk < 16; ++kk) {
        int cb = (kk * 32 + kgrp * 8) * 2;
        bf16x8 a0 = *(const bf16x8*)((const char*)hA + HSWZ(l15 * 1024 + cb));
        bf16x8 a1 = *(const bf16x8*)((const char*)hA + HSWZ((16 + l15) * 1024 + cb));
        acc0 = __builtin_amdgcn_mfma_f32_16x16x32_bf16(a0, wf[8 + kk], acc0, 0, 0, 0);
        acc1 = __builtin_amdgcn_mfma_f32_16x16x32_bf16(a1, wf[8 + kk], acc1, 0, 0, 0);
      }
    } else {
#pragma unroll
      for (int kk = 0; kk < 16; ++kk) {  // h0 part
        int cb = (kk * 32 + kgrp * 8) * 2;
        bf16x8 a0 = *(const bf16x8*)((const char*)xA + HSWZ(l15 * 1024 + cb));
        bf16x8 a1 = *(const bf16x8*)((const char*)xA + HSWZ((16 + l15) * 1024 + cb));
        acc0 = __builtin_amdgcn_mfma_f32_16x16x32_bf16(a0, wf[kk], acc0, 0, 0, 0);
        acc1 = __builtin_amdgcn_mfma_f32_16x16x32_bf16(a1, wf[kk], acc1, 0, 0, 0);
      }
#pragma unroll
      for (int kk = 0; kk < 16; ++kk) {  // h1-prev part
        int cb = (kk * 32 + kgrp * 8) * 2;
        bf16x8 a0 = *(const bf16x8*)((const char*)hA + HSWZ(l15 * 1024 + cb));
        bf16x8 a1 = *(const bf16x8*)((const char*)hA + HSWZ((16 + l15) * 1024 + cb));
        acc0 = __builtin_amdgcn_mfma_f32_16x16x32_bf16(a0, wf[16 + kk], acc0, 0, 0, 0);
        acc1 = __builtin_amdgcn_mfma_f32_16x16x32_bf16(a1, wf[16 + kk], acc1, 0, 0, 0);
      }
    }
#pragma unroll
    for (int j = 0; j < 4; ++j) {
      gates[wave][kgrp * 4 + j][l15] = acc0[j];
      gates[wave][16 + kgrp * 4 + j][l15] = acc1[j];
    }
    __syncthreads();  // gates barrier (also fences hA/xA reuse)

    // ---- epilogue: activations + fire-and-forget tagged store ----
    float i0 = sigm(gates[0][be][ue] + bi0);
    float ff0 = sigm(gates[1][be][ue] + bf0);
    float g0 = tanh_f(gates[2][be][ue] + bg0);
    float o0 = sigm(gates[3][be][ue] + bo0);
    cc0 = ff0 * cc0 + i0 * g0;
    float hv0 = o0 * tanh_f(cc0);
    float i1 = sigm(gates[0][be][ue + 1] + bi1);
    float ff1 = sigm(gates[1][be][ue + 1] + bf1);
    float g1 = tanh_f(gates[2][be][ue + 1] + bg1);
    float o1 = sigm(gates[3][be][ue + 1] + bo1);
    cc1 = ff1 * cc1 + i1 * g1;
    float hv1 = o1 * tanh_f(cc1);
    unsigned tg = TAGW(t);
    u32x2 pv;
    pv.x = tg | (unsigned)f2b(hv0);
    pv.y = tg | (unsigned)f2b(hv1);
    unsigned* hp = myring + (size_t)(t & (RING - 1)) * SLOT_U32 + (size_t)be * 512 + u0 + ue;
    llc_store8(hp, pv);
    // keep store data/addr regs live until next stage's vmcnt(0) drains the store
    asm volatile("" :: "v"(pv), "v"(hp));
  }
}

// ---------------- main kernel: 256 WGs, role = blockIdx%8 (XCD round-robin) ----------------
__global__ void __launch_bounds__(256, 1) lstm_main(
    const unsigned short* __restrict__ xb,
    const unsigned short* __restrict__ wl0,
    const unsigned short* __restrict__ wl1,
    const unsigned short* __restrict__ wfcp,
    const float* __restrict__ b0,
    const float* __restrict__ b1,
    const float* __restrict__ bfc,
    unsigned* __restrict__ h0r,
    unsigned* __restrict__ h1r,
    int* flags,
    float* __restrict__ out) {
  __shared__ __align__(16) unsigned short hA[32 * 512];
  __shared__ __align__(16) unsigned short xA[32 * 512];
  __shared__ __align__(16) float gates[4][32][18];
  const int tid = threadIdx.x;
  const int wave = tid >> 6, lane = tid & 63, l15 = lane & 15, kgrp = lane >> 4;
  const int xcd = blockIdx.x & 7;
  const int idx = blockIdx.x >> 3;
  int* l1prog = flags;
  int* fcprog = flags + NL1 * SLOT_STRIDE;

  if (xcd == 0) {
    if (idx < NL0)
      lstm_path<1>(xb, wl0, b0, h0r, h1r, l1prog, fcprog, idx, hA, xA, gates);
  } else if (xcd == 1) {
    if (idx < NL1)
      lstm_path<0>(xb, wl1, b1, h0r, h1r, l1prog, fcprog, idx, hA, xA, gates);
  } else if (xcd == 2 && idx < NFC) {
    const int fcw = idx;
    const int mt = wave >> 1, ntile = wave & 1;
    const int orow = fcw * 32 + ntile * 16 + l15;
    bf16x8 wff[16];
#pragma unroll
    for (int kk = 0; kk < 16; ++kk) {
      wff[kk] = *(const bf16x8*)(wfcp + (size_t)orow * 512 + kk * 32 + kgrp * 8);
      asm volatile("" : "+v"(wff[kk]));
    }
    const float bb = bfc[orow];
    for (int t = 0; t < T_SEQ; ++t) {
      unsigned short* buf = (t & 1) ? xA : hA;  // double buffer -> 1 barrier/step
      stage_tag<0, 1, 0>(h1r + (size_t)(t & (RING - 1)) * SLOT_U32, TAGW(t), buf,
                         nullptr, 0, nullptr, tid);
      __syncthreads();
      if ((t & 3) == 3 && tid == 0) flag_st(fcprog + fcw * SLOT_STRIDE, t + 1);
      f32x4 acc = {0.f, 0.f, 0.f, 0.f};
#pragma unroll
      for (int kk = 0; kk < 16; ++kk) {
        int row = mt * 16 + l15;
        bf16x8 a = *(const bf16x8*)((const char*)buf + HSWZ(row * 1024 + (kk * 32 + kgrp * 8) * 2));
        acc = __builtin_amdgcn_mfma_f32_16x16x32_bf16(a, wff[kk], acc, 0, 0, 0);
      }
#pragma unroll
      for (int j = 0; j < 4; ++j) {
        int b = mt * 16 + kgrp * 4 + j;
        out[((size_t)b * T_SEQ + t) * 256 + orow] = acc[j] + bb;
      }
    }
  }
}

extern "C" void kernel_launch(void* const* d_in, const int* in_sizes, int n_in,
                              void* d_out, int out_size, void* d_ws, size_t ws_size,
                              hipStream_t stream) {
  const float* x    = (const float*)d_in[0];
  const float* wih0 = (const float*)d_in[1];
  const float* whh0 = (const float*)d_in[2];
  const float* b0   = (const float*)d_in[3];
  const float* wih1 = (const float*)d_in[4];
  const float* whh1 = (const float*)d_in[5];
  const float* b1   = (const float*)d_in[6];
  const float* wfc  = (const float*)d_in[7];
  const float* bfc  = (const float*)d_in[8];
  float* outp = (float*)d_out;

  char* ws = (char*)d_ws;
  size_t off = 0;
  unsigned short* wl0p = (unsigned short*)(ws + off); off += (size_t)2048 * 768 * 2;
  unsigned short* wl1p = (unsigned short*)(ws + off); off += (size_t)2048 * 1024 * 2;
  unsigned short* wfcp = (unsigned short*)(ws + off); off += (size_t)256 * 512 * 2;
  unsigned short* xbp  = (unsigned short*)(ws + off); off += (size_t)2048 * 32 * 256 * 2;
  unsigned* h0rp = (unsigned*)(ws + off); off += (size_t)RING * SLOT_U32 * 4;
  unsigned* h1rp = (unsigned*)(ws + off); off += (size_t)RING * SLOT_U32 * 4;
  int* flagsp = (int*)(ws + off); off += (size_t)(NL1 + NFC) * SLOT_STRIDE * sizeof(int);

  lstm_prologue<<<dim3(1024), dim3(256), 0, stream>>>(
      x, wih0, whh0, wih1, whh1, wfc, wl0p, wl1p, wfcp, xbp, h0rp, h1rp, flagsp);

  lstm_main<<<dim3(256), dim3(256), 0, stream>>>(
      xbp, wl0p, wl1p, wfcp, b0, b1, bfc, h0rp, h1rp, flagsp, outp);
}

// Round 10
// 14275.227 us; speedup vs baseline: 1.0822x; 1.0822x over previous
//
#include <hip/hip_runtime.h>

typedef __attribute__((ext_vector_type(8))) short bf16x8;
typedef __attribute__((ext_vector_type(4))) float f32x4;
typedef __attribute__((ext_vector_type(4))) unsigned int u32x4;
typedef __attribute__((ext_vector_type(2))) unsigned int u32x2;

#define T_SEQ 2048
#define RING  32
#define NL0   32
#define NL1   32
#define NFC   8
#define NWG   (NL0 + NL1 + NFC)
#define SLOT_STRIDE 16               // ints; 64B per flag slot
#define SLOT_U32 (32 * 512)          // ring slot: [batch][unit] u32 (tag|bf16)
#define TAGW(t) ((unsigned)((t) + 1) << 16)
#define NEG_INF (-1000000)

// XOR swizzle for 1024B-row-stride LDS tiles (spreads 8 rows over 8 16B slots)
#define HSWZ(o) ((o) ^ ((((o) >> 10) & 7) << 4))

static __device__ __forceinline__ unsigned short f2b(float f) {
  unsigned u = __float_as_uint(f);
  u = (u + 0x7fffu + ((u >> 16) & 1u)) >> 16;
  return (unsigned short)u;
}
static __device__ __forceinline__ float sigm(float x) { return 1.f / (1.f + __expf(-x)); }
static __device__ __forceinline__ float tanh_f(float x) { return 2.f / (1.f + __expf(-2.f * x)) - 1.f; }

// ---- LLC-coherent ops. ALWAYS sc0 sc1 (authoritative) — r9 lesson: sc0-only
// spins can read stale-valid local lines forever.
static __device__ __forceinline__ u32x4 llc_load16(const void* p) {
  u32x4 v;
  asm volatile("global_load_dwordx4 %0, %1, off sc0 sc1" : "=v"(v) : "v"(p) : "memory");
  return v;
}
static __device__ __forceinline__ void llc_store8(void* p, u32x2 v) {
  asm volatile("global_store_dwordx2 %0, %1, off sc0 sc1" :: "v"(p), "v"(v) : "memory");
}
static __device__ __forceinline__ void vmwait() {
  asm volatile("s_waitcnt vmcnt(0)" ::: "memory");
}
// flag ops: compiler-generated relaxed system-scope atomics (round-5-proven)
static __device__ __forceinline__ int flag_ld(const int* p) {
  return __hip_atomic_load(p, __ATOMIC_RELAXED, __HIP_MEMORY_SCOPE_SYSTEM);
}
static __device__ __forceinline__ void flag_st(int* p, int v) {
  __hip_atomic_store(p, v, __ATOMIC_RELAXED, __HIP_MEMORY_SCOPE_SYSTEM);
}

// round-5-proven fallback spin: lanes 0-31 check s0>=n0, 32-63 check s1>=n1,
// lanes 0-7 additionally sf>=nf. Needs of NEG_INF disable a group.
static __device__ void spin_flags(const int* s0, int n0, const int* s1, int n1,
                                  const int* sf, int nf) {
  if (threadIdx.x < 64) {
    const int lane = threadIdx.x;
    const int* p1 = (lane < 32) ? (s0 + lane * SLOT_STRIDE) : (s1 + (lane - 32) * SLOT_STRIDE);
    const int need1 = (lane < 32) ? n0 : n1;
    const int* p2 = sf + (lane & 7) * SLOT_STRIDE;
    const bool chk2 = (lane < 8) && (nf > NEG_INF);
    for (;;) {
      int v1 = flag_ld(p1);
      int v2 = chk2 ? flag_ld(p2) : 0x7fffffff;
      int ok = (v1 >= need1) && (!chk2 || (v2 >= nf));
      if (__all(ok)) break;
    }
  }
  __syncthreads();
}

// issue one full stage round: 16 chunks/ring of 16B per thread (64KB/ring)
template <int TWO>
static __device__ __forceinline__ void issue_stage(u32x4* vh, u32x4* vx,
                                                   const unsigned* srcA, const unsigned* srcB,
                                                   int tid) {
#pragma unroll
  for (int k = 0; k < 16; ++k)
    vh[k] = llc_load16((const char*)srcA + ((size_t)tid + k * 256) * 16);
  if (TWO) {
#pragma unroll
    for (int k = 0; k < 16; ++k)
      vx[k] = llc_load16((const char*)srcB + ((size_t)tid + k * 256) * 16);
  }
}

// verify embedded tags on already-loaded chunks; pack fresh ones (strip tags)
// into swizzled LDS; retry ONLY stale chunks via sc1 loads (rare, bounded).
template <int TWO>
static __device__ void verify_pack(u32x4* vh, u32x4* vx,
                                   const unsigned* srcA, unsigned tagA, unsigned short* dstA,
                                   const unsigned* srcB, unsigned tagB, unsigned short* dstB,
                                   int tid) {
  constexpr int NCH = TWO ? 32 : 16;
  unsigned mask = TWO ? 0xffffffffu : 0xffffu;
  for (;;) {
    unsigned nm = 0;
#pragma unroll
    for (int k = 0; k < NCH; ++k)
      if ((mask >> k) & 1u) {
        u32x4 w = (k < 16) ? vh[k] : vx[k - 16];
        unsigned tw = (k < 16) ? tagA : tagB;
        unsigned d = ((w.x ^ tw) | (w.y ^ tw) | (w.z ^ tw) | (w.w ^ tw)) & 0xffff0000u;
        if (d == 0) {
          int c = tid + (k & 15) * 256;
          u32x2 p;
          p.x = (w.x & 0xffffu) | (w.y << 16);
          p.y = (w.z & 0xffffu) | (w.w << 16);
          int off = (c >> 7) * 1024 + (c & 127) * 8;
          unsigned short* dst = (k < 16) ? dstA : dstB;
          *(u32x2*)((char*)dst + HSWZ(off)) = p;
        } else {
          nm |= 1u << k;
        }
      }
    if (!nm) return;
#pragma unroll
    for (int k = 0; k < NCH; ++k)
      if ((nm >> k) & 1u) {
        const unsigned* s = (k < 16) ? srcA : srcB;
        u32x4 w = llc_load16((const char*)s + ((size_t)tid + (k & 15) * 256) * 16);
        if (k < 16) vh[k] = w; else vx[k - 16] = w;
      }
    vmwait();
    mask = nm;
  }
}

// ---------------- prologue: pack weights bf16, transpose x, init rings ----------------
__global__ void lstm_prologue(
    const float* __restrict__ x, const float* __restrict__ wih0, const float* __restrict__ whh0,
    const float* __restrict__ wih1, const float* __restrict__ whh1, const float* __restrict__ wfc,
    unsigned short* __restrict__ wl0, unsigned short* __restrict__ wl1,
    unsigned short* __restrict__ wfcp, unsigned short* __restrict__ xb,
    unsigned* __restrict__ h0r, unsigned* __restrict__ h1r,
    int* __restrict__ flags) {
  size_t tid = (size_t)blockIdx.x * blockDim.x + threadIdx.x;
  size_t nthr = (size_t)gridDim.x * blockDim.x;
  for (size_t i = tid; i < (size_t)2048 * 768; i += nthr) {
    int r = (int)(i / 768), k = (int)(i % 768);
    float v = (k < 256) ? wih0[(size_t)r * 256 + k] : whh0[(size_t)r * 512 + (k - 256)];
    wl0[i] = f2b(v);
  }
  for (size_t i = tid; i < (size_t)2048 * 1024; i += nthr) {
    int r = (int)(i >> 10), k = (int)(i & 1023);
    float v = (k < 512) ? wih1[((size_t)r << 9) + k] : whh1[((size_t)r << 9) + (k - 512)];
    wl1[i] = f2b(v);
  }
  for (size_t i = tid; i < 131072; i += nthr) wfcp[i] = f2b(wfc[i]);
  // xb: [T][B][256] bf16 from x [B][T][256] f32
  for (size_t i = tid; i < (size_t)16777216; i += nthr) {
    int ii = (int)(i & 255), b = (int)((i >> 8) & 31), t = (int)(i >> 13);
    xb[i] = f2b(x[((size_t)b * 2048 + t) * 256 + ii]);
  }
  for (size_t i = tid; i < (size_t)NWG * SLOT_STRIDE; i += nthr) flags[i] = 0;
  // slot for t=-1 (slot RING-1): value 0, tag 0 == TAGW(-1)
  for (size_t i = tid; i < SLOT_U32; i += nthr) {
    h0r[(size_t)(RING - 1) * SLOT_U32 + i] = 0;
    h1r[(size_t)(RING - 1) * SLOT_U32 + i] = 0;
  }
}

// ---------------- LSTM layer workgroup body ----------------
template <int ISL0>
static __device__ void lstm_path(
    const unsigned short* __restrict__ xb, const unsigned short* __restrict__ wl,
    const float* __restrict__ bias,
    unsigned* __restrict__ h0r, unsigned* __restrict__ h1r,
    int* s0, int* s1, int* sf, int wid2,
    unsigned short* hA, unsigned short* xA, float (*gates)[32][18], int* gok) {
  const int tid = threadIdx.x;
  const int wave = tid >> 6, lane = tid & 63, l15 = lane & 15, kgrp = lane >> 4;
  const int u0 = wid2 * 16;
  constexpr int K = ISL0 ? 768 : 1024;
  constexpr int NKW = ISL0 ? 24 : 32;
  const unsigned short* wrow = wl + (size_t)(wave * 512 + u0 + l15) * K;

  bf16x8 wf[NKW];
#pragma unroll
  for (int kk = 0; kk < NKW; ++kk) wf[kk] = *(const bf16x8*)(wrow + kk * 32 + kgrp * 8);

  const int ue = 2 * (tid & 7);
  const int be = tid >> 3;
  const float bi0 = bias[0 * 512 + u0 + ue], bi1 = bias[0 * 512 + u0 + ue + 1];
  const float bf0 = bias[1 * 512 + u0 + ue], bf1 = bias[1 * 512 + u0 + ue + 1];
  const float bg0 = bias[2 * 512 + u0 + ue], bg1 = bias[2 * 512 + u0 + ue + 1];
  const float bo0 = bias[3 * 512 + u0 + ue], bo1 = bias[3 * 512 + u0 + ue + 1];
  float cc0 = 0.f, cc1 = 0.f;
  unsigned* myring = ISL0 ? h0r : h1r;
  int* myslot = (ISL0 ? s0 : s1) + wid2 * SLOT_STRIDE;

  for (int t = 0; t < T_SEQ; ++t) {
    // x fragment prefetch (L0; static data)
    bf16x8 xf0[8], xf1[8];
    if (ISL0) {
      const unsigned short* xt = xb + (size_t)t * (32 * 256);
#pragma unroll
      for (int kk = 0; kk < 8; ++kk) {
        xf0[kk] = *(const bf16x8*)(xt + l15 * 256 + kk * 32 + kgrp * 8);
        xf1[kk] = *(const bf16x8*)(xt + (16 + l15) * 256 + kk * 32 + kgrp * 8);
      }
    }

    const unsigned* srcA = myring + (size_t)((t - 1) & (RING - 1)) * SLOT_U32;
    const unsigned tagA = TAGW(t - 1);
    const unsigned* srcB = ISL0 ? nullptr : (h0r + (size_t)(t & (RING - 1)) * SLOT_U32);
    const unsigned tagB = TAGW(t);
    const int n0 = ISL0 ? t : (t + 1);
    const int n1 = ISL0 ? (t - (RING - 1)) : t;
    const int nf = ISL0 ? NEG_INF : (t - (RING - 1));

    // ---- speculative: stage loads + flag loads in ONE round trip ----
    u32x4 vh[16], vx[16];
    issue_stage<!ISL0>(vh, vx, srcA, srcB, tid);
    int v1 = 0x7fffffff, v2 = 0x7fffffff;
    if (tid < 64) {
      const int* p1 = (lane < 32) ? (s0 + lane * SLOT_STRIDE) : (s1 + (lane - 32) * SLOT_STRIDE);
      asm volatile("global_load_dword %0, %1, off sc0 sc1" : "=v"(v1) : "v"(p1) : "memory");
      if (lane < 8 && nf > NEG_INF) {
        const int* p2 = sf + lane * SLOT_STRIDE;
        asm volatile("global_load_dword %0, %1, off sc0 sc1" : "=v"(v2) : "v"(p2) : "memory");
      }
    }
    // L0 x-part MFMAs overlap the in-flight loads (register-only)
    f32x4 acc0 = {0.f, 0.f, 0.f, 0.f}, acc1 = {0.f, 0.f, 0.f, 0.f};
    if (ISL0) {
#pragma unroll
      for (int kk = 0; kk < 8; ++kk) {
        acc0 = __builtin_amdgcn_mfma_f32_16x16x32_bf16(xf0[kk], wf[kk], acc0, 0, 0, 0);
        acc1 = __builtin_amdgcn_mfma_f32_16x16x32_bf16(xf1[kk], wf[kk], acc1, 0, 0, 0);
      }
    }
    vmwait();
    if (tid < 64) {
      const int need1 = (lane < 32) ? n0 : n1;
      int ok = (v1 >= need1) && (v2 >= nf || lane >= 8);
      ok = __all(ok);
      if (tid == 0) *gok = ok;
    }
    __syncthreads();
    if (!*gok) {  // speculation missed: proven r5 spin, then re-stage
      spin_flags(s0, n0, s1, n1, sf, nf);
      issue_stage<!ISL0>(vh, vx, srcA, srcB, tid);
      vmwait();
    }
    verify_pack<!ISL0>(vh, vx, srcA, tagA, hA, srcB, tagB, xA, tid);
    __syncthreads();  // all packs done; LDS tiles ready

    // ---- gates MFMA: h-parts from LDS ----
    if (ISL0) {
#pragma unroll
      for (int kk = 0; kk < 16; ++kk) {
        int cb = (kk * 32 + kgrp * 8) * 2;
        bf16x8 a0 = *(const bf16x8*)((const char*)hA + HSWZ(l15 * 1024 + cb));
        bf16x8 a1 = *(const bf16x8*)((const char*)hA + HSWZ((16 + l15) * 1024 + cb));
        acc0 = __builtin_amdgcn_mfma_f32_16x16x32_bf16(a0, wf[8 + kk], acc0, 0, 0, 0);
        acc1 = __builtin_amdgcn_mfma_f32_16x16x32_bf16(a1, wf[8 + kk], acc1, 0, 0, 0);
      }
    } else {
#pragma unroll
      for (int kk = 0; kk < 16; ++kk) {  // h0[t] part
        int cb = (kk * 32 + kgrp * 8) * 2;
        bf16x8 a0 = *(const bf16x8*)((const char*)xA + HSWZ(l15 * 1024 + cb));
        bf16x8 a1 = *(const bf16x8*)((const char*)xA + HSWZ((16 + l15) * 1024 + cb));
        acc0 = __builtin_amdgcn_mfma_f32_16x16x32_bf16(a0, wf[kk], acc0, 0, 0, 0);
        acc1 = __builtin_amdgcn_mfma_f32_16x16x32_bf16(a1, wf[kk], acc1, 0, 0, 0);
      }
#pragma unroll
      for (int kk = 0; kk < 16; ++kk) {  // h1[t-1] part
        int cb = (kk * 32 + kgrp * 8) * 2;
        bf16x8 a0 = *(const bf16x8*)((const char*)hA + HSWZ(l15 * 1024 + cb));
        bf16x8 a1 = *(const bf16x8*)((const char*)hA + HSWZ((16 + l15) * 1024 + cb));
        acc0 = __builtin_amdgcn_mfma_f32_16x16x32_bf16(a0, wf[16 + kk], acc0, 0, 0, 0);
        acc1 = __builtin_amdgcn_mfma_f32_16x16x32_bf16(a1, wf[16 + kk], acc1, 0, 0, 0);
      }
    }
    // C/D: col(l15)=unit, row(kgrp*4+j)=batch.  gates[gate][batch][unit]
#pragma unroll
    for (int j = 0; j < 4; ++j) {
      gates[wave][kgrp * 4 + j][l15] = acc0[j];
      gates[wave][16 + kgrp * 4 + j][l15] = acc1[j];
    }
    __syncthreads();

    // ---- epilogue: activations; tagged fire-and-forget store (no ACK drain) ----
    float i0 = sigm(gates[0][be][ue] + bi0);
    float ff0 = sigm(gates[1][be][ue] + bf0);
    float g0 = tanh_f(gates[2][be][ue] + bg0);
    float o0 = sigm(gates[3][be][ue] + bo0);
    cc0 = ff0 * cc0 + i0 * g0;
    float hv0 = o0 * tanh_f(cc0);
    float i1 = sigm(gates[0][be][ue + 1] + bi1);
    float ff1 = sigm(gates[1][be][ue + 1] + bf1);
    float g1 = tanh_f(gates[2][be][ue + 1] + bg1);
    float o1 = sigm(gates[3][be][ue + 1] + bo1);
    cc1 = ff1 * cc1 + i1 * g1;
    float hv1 = o1 * tanh_f(cc1);
    unsigned tg = TAGW(t);
    u32x2 pv;
    pv.x = tg | (unsigned)f2b(hv0);
    pv.y = tg | (unsigned)f2b(hv1);
    llc_store8(myring + (size_t)(t & (RING - 1)) * SLOT_U32 + (size_t)be * 512 + u0 + ue, pv);
    __syncthreads();  // all stores ISSUED (order covered by tags, not ACKs)
    if (tid == 0) flag_st(myslot, t + 1);
  }
}

// ---------------- main persistent pipelined kernel ----------------
__global__ void __launch_bounds__(256) lstm_main(
    const unsigned short* __restrict__ xb,
    const unsigned short* __restrict__ wl0,
    const unsigned short* __restrict__ wl1,
    const unsigned short* __restrict__ wfcp,
    const float* __restrict__ b0,
    const float* __restrict__ b1,
    const float* __restrict__ bfc,
    unsigned* __restrict__ h0r,
    unsigned* __restrict__ h1r,
    int* flags,
    float* __restrict__ out) {
  __shared__ __align__(16) unsigned short hA[32 * 512];
  __shared__ __align__(16) unsigned short xA[32 * 512];
  __shared__ __align__(16) float gates[4][32][18];
  __shared__ int gok;
  const int tid = threadIdx.x;
  const int wave = tid >> 6, lane = tid & 63, l15 = lane & 15, kgrp = lane >> 4;
  const int wid = blockIdx.x;
  int* s0 = flags;
  int* s1 = flags + NL0 * SLOT_STRIDE;
  int* sf = flags + (NL0 + NL1) * SLOT_STRIDE;

  if (wid < NL0) {
    lstm_path<1>(xb, wl0, b0, h0r, h1r, s0, s1, sf, wid, hA, xA, gates, &gok);
  } else if (wid < NL0 + NL1) {
    lstm_path<0>(xb, wl1, b1, h0r, h1r, s0, s1, sf, wid - NL0, hA, xA, gates, &gok);
  } else {
    const int fcw = wid - NL0 - NL1;  // 0..7
    const int mt = wave >> 1, ntile = wave & 1;
    const int orow = fcw * 32 + ntile * 16 + l15;
    bf16x8 wff[16];
#pragma unroll
    for (int kk = 0; kk < 16; ++kk)
      wff[kk] = *(const bf16x8*)(wfcp + (size_t)orow * 512 + kk * 32 + kgrp * 8);
    const float bb = bfc[orow];
    for (int t = 0; t < T_SEQ; ++t) {
      const unsigned* srcA = h1r + (size_t)(t & (RING - 1)) * SLOT_U32;
      const unsigned tagA = TAGW(t);
      unsigned short* buf = (t & 1) ? xA : hA;  // double buffer
      u32x4 vh[16], vx[16];
      issue_stage<0>(vh, vx, srcA, nullptr, tid);
      int v1 = 0x7fffffff;
      if (tid < 64 && lane >= 32) {
        const int* p1 = s1 + (lane - 32) * SLOT_STRIDE;
        asm volatile("global_load_dword %0, %1, off sc0 sc1" : "=v"(v1) : "v"(p1) : "memory");
      }
      vmwait();
      if (tid < 64) {
        int ok = __all(lane < 32 || v1 >= t + 1);
        if (tid == 0) gok = ok;
      }
      __syncthreads();
      if (!gok) {
        spin_flags(s0, NEG_INF, s1, t + 1, sf, NEG_INF);
        issue_stage<0>(vh, vx, srcA, nullptr, tid);
        vmwait();
      }
      verify_pack<0>(vh, vx, srcA, tagA, buf, nullptr, 0, nullptr, tid);
      __syncthreads();
      if (tid == 0) flag_st(sf + fcw * SLOT_STRIDE, t + 1);  // h1[t] consumed
      f32x4 acc = {0.f, 0.f, 0.f, 0.f};
#pragma unroll
      for (int kk = 0; kk < 16; ++kk) {
        int row = mt * 16 + l15;
        bf16x8 a = *(const bf16x8*)((const char*)buf + HSWZ(row * 1024 + (kk * 32 + kgrp * 8) * 2));
        acc = __builtin_amdgcn_mfma_f32_16x16x32_bf16(a, wff[kk], acc, 0, 0, 0);
      }
#pragma unroll
      for (int j = 0; j < 4; ++j) {
        int b = mt * 16 + kgrp * 4 + j;
        out[((size_t)b * T_SEQ + t) * 256 + orow] = acc[j] + bb;
      }
    }
  }
}

extern "C" void kernel_launch(void* const* d_in, const int* in_sizes, int n_in,
                              void* d_out, int out_size, void* d_ws, size_t ws_size,
                              hipStream_t stream) {
  const float* x    = (const float*)d_in[0];
  const float* wih0 = (const float*)d_in[1];
  const float* whh0 = (const float*)d_in[2];
  const float* b0   = (const float*)d_in[3];
  const float* wih1 = (const float*)d_in[4];
  const float* whh1 = (const float*)d_in[5];
  const float* b1   = (const float*)d_in[6];
  const float* wfc  = (const float*)d_in[7];
  const float* bfc  = (const float*)d_in[8];
  float* outp = (float*)d_out;

  char* ws = (char*)d_ws;
  size_t off = 0;
  unsigned short* wl0p = (unsigned short*)(ws + off); off += (size_t)2048 * 768 * 2;
  unsigned short* wl1p = (unsigned short*)(ws + off); off += (size_t)2048 * 1024 * 2;
  unsigned short* wfcp = (unsigned short*)(ws + off); off += (size_t)256 * 512 * 2;
  unsigned short* xbp  = (unsigned short*)(ws + off); off += (size_t)2048 * 32 * 256 * 2;
  unsigned* h0rp = (unsigned*)(ws + off); off += (size_t)RING * SLOT_U32 * 4;
  unsigned* h1rp = (unsigned*)(ws + off); off += (size_t)RING * SLOT_U32 * 4;
  int* flagsp = (int*)(ws + off); off += (size_t)NWG * SLOT_STRIDE * sizeof(int);

  lstm_prologue<<<dim3(1024), dim3(256), 0, stream>>>(
      x, wih0, whh0, wih1, whh1, wfc, wl0p, wl1p, wfcp, xbp, h0rp, h1rp, flagsp);

  lstm_main<<<dim3(NWG), dim3(256), 0, stream>>>(
      xbp, wl0p, wl1p, wfcp, b0, b1, bfc, h0rp, h1rp, flagsp, outp);
}

// Round 11
// 12235.568 us; speedup vs baseline: 1.2626x; 1.1667x over previous
//
#include <hip/hip_runtime.h>

typedef __attribute__((ext_vector_type(8))) short bf16x8;
typedef __attribute__((ext_vector_type(4))) float f32x4;
typedef __attribute__((ext_vector_type(4))) unsigned int u32x4;
typedef __attribute__((ext_vector_type(2))) unsigned int u32x2;

#define T_SEQ 2048
#define RING  32
#define NL0   32
#define NL1   32
#define NFC   8
#define NWG   (NL0 + NL1 + NFC)
#define SLOT_STRIDE 16               // ints; 64B per flag slot
#define SLOT_U32 (32 * 512)          // ring slot: [batch][unit] u32 (tag|bf16)
#define TAGW(t) ((unsigned)((t) + 1) << 16)
#define NEG_INF (-1000000)

// XOR swizzle for 1024B-row-stride LDS tiles (spreads 8 rows over 8 16B slots)
#define HSWZ(o) ((o) ^ ((((o) >> 10) & 7) << 4))

static __device__ __forceinline__ unsigned short f2b(float f) {
  unsigned u = __float_as_uint(f);
  u = (u + 0x7fffu + ((u >> 16) & 1u)) >> 16;
  return (unsigned short)u;
}
static __device__ __forceinline__ float sigm(float x) { return 1.f / (1.f + __expf(-x)); }
static __device__ __forceinline__ float tanh_f(float x) { return 2.f / (1.f + __expf(-2.f * x)) - 1.f; }

// ---- LLC-coherent ops. ALWAYS sc0 sc1 — r9 lesson: sc0-only spins can read
// stale-valid local lines forever.
static __device__ __forceinline__ u32x4 llc_load16(const void* p) {
  u32x4 v;
  asm volatile("global_load_dwordx4 %0, %1, off sc0 sc1" : "=v"(v) : "v"(p) : "memory");
  return v;
}
static __device__ __forceinline__ void llc_store8(void* p, u32x2 v) {
  asm volatile("global_store_dwordx2 %0, %1, off sc0 sc1" :: "v"(p), "v"(v) : "memory");
}
static __device__ __forceinline__ void vmwait() {
  asm volatile("s_waitcnt vmcnt(0)" ::: "memory");
}
// flag ops: compiler-generated relaxed system-scope atomics (round-5-proven)
static __device__ __forceinline__ int flag_ld(const int* p) {
  return __hip_atomic_load(p, __ATOMIC_RELAXED, __HIP_MEMORY_SCOPE_SYSTEM);
}
static __device__ __forceinline__ void flag_st(int* p, int v) {
  __hip_atomic_store(p, v, __ATOMIC_RELAXED, __HIP_MEMORY_SCOPE_SYSTEM);
}

// round-5-proven poll: lanes 0-31 check s0>=n0, 32-63 check s1>=n1, lanes 0-7
// additionally sf>=nf (NEG_INF disables). Ends with a full __syncthreads,
// whose compiler-emitted vmcnt(0) also drains OUR in-flight h stores (off the
// critical path: it overlaps the spin).
static __device__ void spin_flags(const int* s0, int n0, const int* s1, int n1,
                                  const int* sf, int nf) {
  if (threadIdx.x < 64) {
    const int lane = threadIdx.x;
    const int* p1 = (lane < 32) ? (s0 + lane * SLOT_STRIDE) : (s1 + (lane - 32) * SLOT_STRIDE);
    const int need1 = (lane < 32) ? n0 : n1;
    const int* p2 = sf + (lane & 7) * SLOT_STRIDE;
    const bool chk2 = (lane < 8) && (nf > NEG_INF);
    for (;;) {
      int v1 = flag_ld(p1);
      int v2 = chk2 ? flag_ld(p2) : 0x7fffffff;
      int ok = (v1 >= need1) && (!chk2 || (v2 >= nf));
      if (__all(ok)) break;
    }
  }
  __syncthreads();
}

// issue one full stage round: 16 chunks/ring of 16B per thread (64KB/ring)
template <int TWO>
static __device__ __forceinline__ void issue_stage(u32x4* vh, u32x4* vx,
                                                   const unsigned* srcA, const unsigned* srcB,
                                                   int tid) {
#pragma unroll
  for (int k = 0; k < 16; ++k)
    vh[k] = llc_load16((const char*)srcA + ((size_t)tid + k * 256) * 16);
  if (TWO) {
#pragma unroll
    for (int k = 0; k < 16; ++k)
      vx[k] = llc_load16((const char*)srcB + ((size_t)tid + k * 256) * 16);
  }
}

// verify embedded tags; pack fresh chunks (strip tags) into swizzled LDS;
// retry ONLY stale chunks (rare: flag/data issue skew window). r10-proven.
template <int TWO>
static __device__ void verify_pack(u32x4* vh, u32x4* vx,
                                   const unsigned* srcA, unsigned tagA, unsigned short* dstA,
                                   const unsigned* srcB, unsigned tagB, unsigned short* dstB,
                                   int tid) {
  constexpr int NCH = TWO ? 32 : 16;
  unsigned mask = TWO ? 0xffffffffu : 0xffffu;
  for (;;) {
    unsigned nm = 0;
#pragma unroll
    for (int k = 0; k < NCH; ++k)
      if ((mask >> k) & 1u) {
        u32x4 w = (k < 16) ? vh[k] : vx[k - 16];
        unsigned tw = (k < 16) ? tagA : tagB;
        unsigned d = ((w.x ^ tw) | (w.y ^ tw) | (w.z ^ tw) | (w.w ^ tw)) & 0xffff0000u;
        if (d == 0) {
          int c = tid + (k & 15) * 256;
          u32x2 p;
          p.x = (w.x & 0xffffu) | (w.y << 16);
          p.y = (w.z & 0xffffu) | (w.w << 16);
          int off = (c >> 7) * 1024 + (c & 127) * 8;
          unsigned short* dst = (k < 16) ? dstA : dstB;
          *(u32x2*)((char*)dst + HSWZ(off)) = p;
        } else {
          nm |= 1u << k;
        }
      }
    if (!nm) return;
#pragma unroll
    for (int k = 0; k < NCH; ++k)
      if ((nm >> k) & 1u) {
        const unsigned* s = (k < 16) ? srcA : srcB;
        u32x4 w = llc_load16((const char*)s + ((size_t)tid + (k & 15) * 256) * 16);
        if (k < 16) vh[k] = w; else vx[k - 16] = w;
      }
    vmwait();
    mask = nm;
  }
}

// ---------------- prologue: pack weights bf16, transpose x, init rings ----------------
__global__ void lstm_prologue(
    const float* __restrict__ x, const float* __restrict__ wih0, const float* __restrict__ whh0,
    const float* __restrict__ wih1, const float* __restrict__ whh1, const float* __restrict__ wfc,
    unsigned short* __restrict__ wl0, unsigned short* __restrict__ wl1,
    unsigned short* __restrict__ wfcp, unsigned short* __restrict__ xb,
    unsigned* __restrict__ h0r, unsigned* __restrict__ h1r,
    int* __restrict__ flags) {
  size_t tid = (size_t)blockIdx.x * blockDim.x + threadIdx.x;
  size_t nthr = (size_t)gridDim.x * blockDim.x;
  for (size_t i = tid; i < (size_t)2048 * 768; i += nthr) {
    int r = (int)(i / 768), k = (int)(i % 768);
    float v = (k < 256) ? wih0[(size_t)r * 256 + k] : whh0[(size_t)r * 512 + (k - 256)];
    wl0[i] = f2b(v);
  }
  for (size_t i = tid; i < (size_t)2048 * 1024; i += nthr) {
    int r = (int)(i >> 10), k = (int)(i & 1023);
    float v = (k < 512) ? wih1[((size_t)r << 9) + k] : whh1[((size_t)r << 9) + (k - 512)];
    wl1[i] = f2b(v);
  }
  for (size_t i = tid; i < 131072; i += nthr) wfcp[i] = f2b(wfc[i]);
  // xb: [T][B][256] bf16 from x [B][T][256] f32
  for (size_t i = tid; i < (size_t)16777216; i += nthr) {
    int ii = (int)(i & 255), b = (int)((i >> 8) & 31), t = (int)(i >> 13);
    xb[i] = f2b(x[((size_t)b * 2048 + t) * 256 + ii]);
  }
  for (size_t i = tid; i < (size_t)NWG * SLOT_STRIDE; i += nthr) flags[i] = 0;
  // slot for t=-1 (slot RING-1): value 0, tag 0 == TAGW(-1)
  for (size_t i = tid; i < SLOT_U32; i += nthr) {
    h0r[(size_t)(RING - 1) * SLOT_U32 + i] = 0;
    h1r[(size_t)(RING - 1) * SLOT_U32 + i] = 0;
  }
}

// ---------------- LSTM layer workgroup body ----------------
template <int ISL0>
static __device__ void lstm_path(
    const unsigned short* __restrict__ xb, const unsigned short* __restrict__ wl,
    const float* __restrict__ bias,
    unsigned* __restrict__ h0r, unsigned* __restrict__ h1r,
    int* s0, int* s1, int* sf, int wid2,
    unsigned short* hA, unsigned short* xA, float (*gates)[32][18]) {
  const int tid = threadIdx.x;
  const int wave = tid >> 6, lane = tid & 63, l15 = lane & 15, kgrp = lane >> 4;
  const int u0 = wid2 * 16;
  constexpr int K = ISL0 ? 768 : 1024;
  constexpr int NKW = ISL0 ? 24 : 32;
  const unsigned short* wrow = wl + (size_t)(wave * 512 + u0 + l15) * K;

  bf16x8 wf[NKW];
#pragma unroll
  for (int kk = 0; kk < NKW; ++kk) wf[kk] = *(const bf16x8*)(wrow + kk * 32 + kgrp * 8);

  const int ue = 2 * (tid & 7);
  const int be = tid >> 3;
  const float bi0 = bias[0 * 512 + u0 + ue], bi1 = bias[0 * 512 + u0 + ue + 1];
  const float bf0 = bias[1 * 512 + u0 + ue], bf1 = bias[1 * 512 + u0 + ue + 1];
  const float bg0 = bias[2 * 512 + u0 + ue], bg1 = bias[2 * 512 + u0 + ue + 1];
  const float bo0 = bias[3 * 512 + u0 + ue], bo1 = bias[3 * 512 + u0 + ue + 1];
  float cc0 = 0.f, cc1 = 0.f;
  unsigned* myring = ISL0 ? h0r : h1r;
  int* myslot = (ISL0 ? s0 : s1) + wid2 * SLOT_STRIDE;

  // previous-step store payload/address, kept live across the publish window
  u32x2 pv = {0u, 0u};
  unsigned* hp = myring;

  for (int t = 0; t < T_SEQ; ++t) {
    // x fragment prefetch (L0; static data, off the critical path)
    bf16x8 xf0[8], xf1[8];
    if (ISL0) {
      const unsigned short* xt = xb + (size_t)t * (32 * 256);
#pragma unroll
      for (int kk = 0; kk < 8; ++kk) {
        xf0[kk] = *(const bf16x8*)(xt + l15 * 256 + kk * 32 + kgrp * 8);
        xf1[kk] = *(const bf16x8*)(xt + (16 + l15) * 256 + kk * 32 + kgrp * 8);
      }
    }

    const unsigned* srcA = myring + (size_t)((t - 1) & (RING - 1)) * SLOT_U32;
    const unsigned tagA = TAGW(t - 1);
    const unsigned* srcB = ISL0 ? nullptr : (h0r + (size_t)(t & (RING - 1)) * SLOT_U32);
    const unsigned tagB = TAGW(t);
    const int n0 = ISL0 ? t : (t + 1);
    const int n1 = ISL0 ? (t - (RING - 1)) : t;
    const int nf = ISL0 ? NEG_INF : (t - (RING - 1));

    // ---- poll first (cheap 4B flags), then stage once ----
    spin_flags(s0, n0, s1, n1, sf, nf);
    // liveness pin: last step's fire-and-forget store regs stay reserved until
    // the drain inside spin_flags' closing __syncthreads has retired them.
    asm volatile("" :: "v"(pv), "v"(hp));

    u32x4 vh[16], vx[16];
    issue_stage<!ISL0>(vh, vx, srcA, srcB, tid);

    // L0 x-part MFMAs overlap the in-flight stage loads (register-only)
    f32x4 acc0 = {0.f, 0.f, 0.f, 0.f}, acc1 = {0.f, 0.f, 0.f, 0.f};
    if (ISL0) {
#pragma unroll
      for (int kk = 0; kk < 8; ++kk) {
        acc0 = __builtin_amdgcn_mfma_f32_16x16x32_bf16(xf0[kk], wf[kk], acc0, 0, 0, 0);
        acc1 = __builtin_amdgcn_mfma_f32_16x16x32_bf16(xf1[kk], wf[kk], acc1, 0, 0, 0);
      }
    }
    vmwait();
    verify_pack<!ISL0>(vh, vx, srcA, tagA, hA, srcB, tagB, xA, tid);
    __syncthreads();  // LDS tiles ready

    // ---- gates MFMA: h-parts from LDS ----
    if (ISL0) {
#pragma unroll
      for (int kk = 0; kk < 16; ++kk) {
        int cb = (kk * 32 + kgrp * 8) * 2;
        bf16x8 a0 = *(const bf16x8*)((const char*)hA + HSWZ(l15 * 1024 + cb));
        bf16x8 a1 = *(const bf16x8*)((const char*)hA + HSWZ((16 + l15) * 1024 + cb));
        acc0 = __builtin_amdgcn_mfma_f32_16x16x32_bf16(a0, wf[8 + kk], acc0, 0, 0, 0);
        acc1 = __builtin_amdgcn_mfma_f32_16x16x32_bf16(a1, wf[8 + kk], acc1, 0, 0, 0);
      }
    } else {
#pragma unroll
      for (int kk = 0; kk < 16; ++kk) {  // h0[t] part
        int cb = (kk * 32 + kgrp * 8) * 2;
        bf16x8 a0 = *(const bf16x8*)((const char*)xA + HSWZ(l15 * 1024 + cb));
        bf16x8 a1 = *(const bf16x8*)((const char*)xA + HSWZ((16 + l15) * 1024 + cb));
        acc0 = __builtin_amdgcn_mfma_f32_16x16x32_bf16(a0, wf[kk], acc0, 0, 0, 0);
        acc1 = __builtin_amdgcn_mfma_f32_16x16x32_bf16(a1, wf[kk], acc1, 0, 0, 0);
      }
#pragma unroll
      for (int kk = 0; kk < 16; ++kk) {  // h1[t-1] part
        int cb = (kk * 32 + kgrp * 8) * 2;
        bf16x8 a0 = *(const bf16x8*)((const char*)hA + HSWZ(l15 * 1024 + cb));
        bf16x8 a1 = *(const bf16x8*)((const char*)hA + HSWZ((16 + l15) * 1024 + cb));
        acc0 = __builtin_amdgcn_mfma_f32_16x16x32_bf16(a0, wf[16 + kk], acc0, 0, 0, 0);
        acc1 = __builtin_amdgcn_mfma_f32_16x16x32_bf16(a1, wf[16 + kk], acc1, 0, 0, 0);
      }
    }
    // C/D: col(l15)=unit, row(kgrp*4+j)=batch.  gates[gate][batch][unit]
#pragma unroll
    for (int j = 0; j < 4; ++j) {
      gates[wave][kgrp * 4 + j][l15] = acc0[j];
      gates[wave][16 + kgrp * 4 + j][l15] = acc1[j];
    }
    __syncthreads();

    // ---- epilogue: activations; tagged fire-and-forget publish (no ACK drain) ----
    float i0 = sigm(gates[0][be][ue] + bi0);
    float ff0 = sigm(gates[1][be][ue] + bf0);
    float g0 = tanh_f(gates[2][be][ue] + bg0);
    float o0 = sigm(gates[3][be][ue] + bo0);
    cc0 = ff0 * cc0 + i0 * g0;
    float hv0 = o0 * tanh_f(cc0);
    float i1 = sigm(gates[0][be][ue + 1] + bi1);
    float ff1 = sigm(gates[1][be][ue + 1] + bf1);
    float g1 = tanh_f(gates[2][be][ue + 1] + bg1);
    float o1 = sigm(gates[3][be][ue + 1] + bo1);
    cc1 = ff1 * cc1 + i1 * g1;
    float hv1 = o1 * tanh_f(cc1);
    unsigned tg = TAGW(t);
    pv.x = tg | (unsigned)f2b(hv0);
    pv.y = tg | (unsigned)f2b(hv1);
    hp = myring + (size_t)(t & (RING - 1)) * SLOT_U32 + (size_t)be * 512 + u0 + ue;
    llc_store8(hp, pv);
    // raw barrier: all threads have ISSUED their stores (no vmcnt drain);
    // flag may beat data at LLC — consumers' tag-verify absorbs that race.
    asm volatile("s_barrier" ::: "memory");
    if (tid == 0) flag_st(myslot, t + 1);
  }
}

// ---------------- main persistent pipelined kernel ----------------
__global__ void __launch_bounds__(256) lstm_main(
    const unsigned short* __restrict__ xb,
    const unsigned short* __restrict__ wl0,
    const unsigned short* __restrict__ wl1,
    const unsigned short* __restrict__ wfcp,
    const float* __restrict__ b0,
    const float* __restrict__ b1,
    const float* __restrict__ bfc,
    unsigned* __restrict__ h0r,
    unsigned* __restrict__ h1r,
    int* flags,
    float* __restrict__ out) {
  __shared__ __align__(16) unsigned short hA[32 * 512];
  __shared__ __align__(16) unsigned short xA[32 * 512];
  __shared__ __align__(16) float gates[4][32][18];
  const int tid = threadIdx.x;
  const int wave = tid >> 6, lane = tid & 63, l15 = lane & 15, kgrp = lane >> 4;
  const int wid = blockIdx.x;
  int* s0 = flags;
  int* s1 = flags + NL0 * SLOT_STRIDE;
  int* sf = flags + (NL0 + NL1) * SLOT_STRIDE;

  if (wid < NL0) {
    lstm_path<1>(xb, wl0, b0, h0r, h1r, s0, s1, sf, wid, hA, xA, gates);
  } else if (wid < NL0 + NL1) {
    lstm_path<0>(xb, wl1, b1, h0r, h1r, s0, s1, sf, wid - NL0, hA, xA, gates);
  } else {
    const int fcw = wid - NL0 - NL1;  // 0..7
    const int mt = wave >> 1, ntile = wave & 1;
    const int orow = fcw * 32 + ntile * 16 + l15;
    bf16x8 wff[16];
#pragma unroll
    for (int kk = 0; kk < 16; ++kk)
      wff[kk] = *(const bf16x8*)(wfcp + (size_t)orow * 512 + kk * 32 + kgrp * 8);
    const float bb = bfc[orow];
    for (int t = 0; t < T_SEQ; ++t) {
      const unsigned* srcA = h1r + (size_t)(t & (RING - 1)) * SLOT_U32;
      const unsigned tagA = TAGW(t);
      unsigned short* buf = (t & 1) ? xA : hA;  // double buffer
      spin_flags(s0, NEG_INF, s1, t + 1, sf, NEG_INF);
      u32x4 vh[16], vx[16];
      issue_stage<0>(vh, vx, srcA, nullptr, tid);
      vmwait();
      verify_pack<0>(vh, vx, srcA, tagA, buf, nullptr, 0, nullptr, tid);
      __syncthreads();
      if (tid == 0) flag_st(sf + fcw * SLOT_STRIDE, t + 1);  // h1[t] consumed
      f32x4 acc = {0.f, 0.f, 0.f, 0.f};
#pragma unroll
      for (int kk = 0; kk < 16; ++kk) {
        int row = mt * 16 + l15;
        bf16x8 a = *(const bf16x8*)((const char*)buf + HSWZ(row * 1024 + (kk * 32 + kgrp * 8) * 2));
        acc = __builtin_amdgcn_mfma_f32_16x16x32_bf16(a, wff[kk], acc, 0, 0, 0);
      }
#pragma unroll
      for (int j = 0; j < 4; ++j) {
        int b = mt * 16 + kgrp * 4 + j;
        out[((size_t)b * T_SEQ + t) * 256 + orow] = acc[j] + bb;
      }
    }
  }
}

extern "C" void kernel_launch(void* const* d_in, const int* in_sizes, int n_in,
                              void* d_out, int out_size, void* d_ws, size_t ws_size,
                              hipStream_t stream) {
  const float* x    = (const float*)d_in[0];
  const float* wih0 = (const float*)d_in[1];
  const float* whh0 = (const float*)d_in[2];
  const float* b0   = (const float*)d_in[3];
  const float* wih1 = (const float*)d_in[4];
  const float* whh1 = (const float*)d_in[5];
  const float* b1   = (const float*)d_in[6];
  const float* wfc  = (const float*)d_in[7];
  const float* bfc  = (const float*)d_in[8];
  float* outp = (float*)d_out;

  char* ws = (char*)d_ws;
  size_t off = 0;
  unsigned short* wl0p = (unsigned short*)(ws + off); off += (size_t)2048 * 768 * 2;
  unsigned short* wl1p = (unsigned short*)(ws + off); off += (size_t)2048 * 1024 * 2;
  unsigned short* wfcp = (unsigned short*)(ws + off); off += (size_t)256 * 512 * 2;
  unsigned short* xbp  = (unsigned short*)(ws + off); off += (size_t)2048 * 32 * 256 * 2;
  unsigned* h0rp = (unsigned*)(ws + off); off += (size_t)RING * SLOT_U32 * 4;
  unsigned* h1rp = (unsigned*)(ws + off); off += (size_t)RING * SLOT_U32 * 4;
  int* flagsp = (int*)(ws + off); off += (size_t)NWG * SLOT_STRIDE * sizeof(int);

  lstm_prologue<<<dim3(1024), dim3(256), 0, stream>>>(
      x, wih0, whh0, wih1, whh1, wfc, wl0p, wl1p, wfcp, xbp, h0rp, h1rp, flagsp);

  lstm_main<<<dim3(NWG), dim3(256), 0, stream>>>(
      xbp, wl0p, wl1p, wfcp, b0, b1, bfc, h0rp, h1rp, flagsp, outp);
}

// Round 12
// 8478.250 us; speedup vs baseline: 1.8221x; 1.4432x over previous
//
#include <hip/hip_runtime.h>

typedef __attribute__((ext_vector_type(8))) short bf16x8;
typedef __attribute__((ext_vector_type(4))) float f32x4;
typedef __attribute__((ext_vector_type(4))) unsigned int u32x4;

#define T_SEQ 2048
#define RING  64
#define NL0   32
#define NL1   32
#define NFC   8
#define NWG   (NL0 + NL1 + NFC)
#define SLOT_STRIDE 16  // ints; 64B per slot
#define NEG_INF (-1000000)

// XOR swizzle for 1024B-row-stride LDS tiles (spreads 8 rows over 8 16B slots)
#define HSWZ(o) ((o) ^ ((((o) >> 10) & 7) << 4))

static __device__ __forceinline__ unsigned short f2b(float f) {
  unsigned u = __float_as_uint(f);
  u = (u + 0x7fffu + ((u >> 16) & 1u)) >> 16;
  return (unsigned short)u;
}
static __device__ __forceinline__ float sigm(float x) { return 1.f / (1.f + __expf(-x)); }
static __device__ __forceinline__ float tanh_f(float x) { return 2.f / (1.f + __expf(-2.f * x)) - 1.f; }

// ---- LLC-coherent (cross-XCD) bulk data movement (round-2/5-proven) ----
static __device__ __forceinline__ u32x4 llc_load16(const void* p) {
  u32x4 v;
  asm volatile("global_load_dwordx4 %0, %1, off sc0 sc1" : "=v"(v) : "v"(p) : "memory");
  return v;
}
static __device__ __forceinline__ void llc_store4(void* p, unsigned v) {
  asm volatile("global_store_dword %0, %1, off sc0 sc1" :: "v"(p), "v"(v) : "memory");
}
static __device__ __forceinline__ void vmwait() {
  asm volatile("s_waitcnt vmcnt(0)" ::: "memory");
}
// flag ops: compiler-generated relaxed system-scope atomics (round-5-proven)
static __device__ __forceinline__ int flag_ld(const int* p) {
  return __hip_atomic_load(p, __ATOMIC_RELAXED, __HIP_MEMORY_SCOPE_SYSTEM);
}
static __device__ __forceinline__ void flag_st(int* p, int v) {
  __hip_atomic_store(p, v, __ATOMIC_RELAXED, __HIP_MEMORY_SCOPE_SYSTEM);
}

// round-5-proven wave-parallel poll: lanes 0-31 check s0>=n0, 32-63 check
// s1>=n1, lanes 0-7 additionally sf>=nf. NEG_INF disables a group.
static __device__ void spin_flags(const int* s0, int n0, const int* s1, int n1,
                                  const int* sf, int nf) {
  if (threadIdx.x < 64) {
    const int lane = threadIdx.x;
    const int* p1 = (lane < 32) ? (s0 + lane * SLOT_STRIDE) : (s1 + (lane - 32) * SLOT_STRIDE);
    const int need1 = (lane < 32) ? n0 : n1;
    const int* p2 = sf + (lane & 7) * SLOT_STRIDE;
    const bool chk2 = (lane < 8) && (nf > NEG_INF);
    for (;;) {
      int v1 = flag_ld(p1);
      int v2 = chk2 ? flag_ld(p2) : 0x7fffffff;
      int ok = (v1 >= need1) && (!chk2 || (v2 >= nf));
      if (__all(ok)) break;
    }
  }
  __syncthreads();
}

// ---------------- prologue: pack weights bf16, transpose x, zero state ----------------
__global__ void lstm_prologue(
    const float* __restrict__ x, const float* __restrict__ wih0, const float* __restrict__ whh0,
    const float* __restrict__ wih1, const float* __restrict__ whh1, const float* __restrict__ wfc,
    unsigned short* __restrict__ wl0, unsigned short* __restrict__ wl1,
    unsigned short* __restrict__ wfcp, unsigned short* __restrict__ xb,
    unsigned short* __restrict__ h0r, unsigned short* __restrict__ h1r,
    int* __restrict__ flags) {
  size_t tid = (size_t)blockIdx.x * blockDim.x + threadIdx.x;
  size_t nthr = (size_t)gridDim.x * blockDim.x;
  for (size_t i = tid; i < (size_t)2048 * 768; i += nthr) {
    int r = (int)(i / 768), k = (int)(i % 768);
    float v = (k < 256) ? wih0[(size_t)r * 256 + k] : whh0[(size_t)r * 512 + (k - 256)];
    wl0[i] = f2b(v);
  }
  for (size_t i = tid; i < (size_t)2048 * 1024; i += nthr) {
    int r = (int)(i >> 10), k = (int)(i & 1023);
    float v = (k < 512) ? wih1[((size_t)r << 9) + k] : whh1[((size_t)r << 9) + (k - 512)];
    wl1[i] = f2b(v);
  }
  for (size_t i = tid; i < 131072; i += nthr) wfcp[i] = f2b(wfc[i]);
  // xb: [T][B][256] bf16 from x [B][T][256] f32
  for (size_t i = tid; i < (size_t)16777216; i += nthr) {
    int ii = (int)(i & 255), b = (int)((i >> 8) & 31), t = (int)(i >> 13);
    xb[i] = f2b(x[((size_t)b * 2048 + t) * 256 + ii]);
  }
  for (size_t i = tid; i < (size_t)NWG * SLOT_STRIDE; i += nthr) flags[i] = 0;
  for (size_t i = tid; i < 32 * 512; i += nthr) {
    h0r[(size_t)(RING - 1) * 32 * 512 + i] = 0;
    h1r[(size_t)(RING - 1) * 32 * 512 + i] = 0;
  }
}

// ---------------- LSTM layer workgroup body ----------------
template <int ISL0>
static __device__ void lstm_path(
    const unsigned short* __restrict__ xb, const unsigned short* __restrict__ wl,
    const float* __restrict__ bias,
    unsigned short* __restrict__ h0r, unsigned short* __restrict__ h1r,
    int* s0, int* s1, int* sf, int wid2,
    unsigned short* hA, unsigned short* xA, float (*gates)[32][18]) {
  const int tid = threadIdx.x;
  const int wave = tid >> 6, lane = tid & 63, l15 = lane & 15, kgrp = lane >> 4;
  const int u0 = wid2 * 16;
  constexpr int K = ISL0 ? 768 : 1024;
  constexpr int NKW = ISL0 ? 24 : 32;
  const unsigned short* wrow = wl + (size_t)(wave * 512 + u0 + l15) * K;

  bf16x8 wf[NKW];
#pragma unroll
  for (int kk = 0; kk < NKW; ++kk) wf[kk] = *(const bf16x8*)(wrow + kk * 32 + kgrp * 8);

  const int ue = 2 * (tid & 7);
  const int be = tid >> 3;
  const float bi0 = bias[0 * 512 + u0 + ue], bi1 = bias[0 * 512 + u0 + ue + 1];
  const float bf0 = bias[1 * 512 + u0 + ue], bf1 = bias[1 * 512 + u0 + ue + 1];
  const float bg0 = bias[2 * 512 + u0 + ue], bg1 = bias[2 * 512 + u0 + ue + 1];
  const float bo0 = bias[3 * 512 + u0 + ue], bo1 = bias[3 * 512 + u0 + ue + 1];
  float cc0 = 0.f, cc1 = 0.f;
  unsigned short* myring = ISL0 ? h0r : h1r;
  int* myslot = (ISL0 ? s0 : s1) + wid2 * SLOT_STRIDE;

  for (int t = 0; t < T_SEQ; ++t) {
    f32x4 acc0 = {0.f, 0.f, 0.f, 0.f}, acc1 = {0.f, 0.f, 0.f, 0.f};

    if (ISL0) {
      // x fragment prefetch (static data, issued before the poll)
      bf16x8 xf0[8], xf1[8];
      const unsigned short* xt = xb + (size_t)t * (32 * 256);
#pragma unroll
      for (int kk = 0; kk < 8; ++kk) {
        xf0[kk] = *(const bf16x8*)(xt + l15 * 256 + kk * 32 + kgrp * 8);
        xf1[kk] = *(const bf16x8*)(xt + (16 + l15) * 256 + kk * 32 + kgrp * 8);
      }
      // the real wait: peers' h0[t-1]; L1 progress = ring guard
      spin_flags(s0, t, s1, t - (RING - 1), sf, NEG_INF);

      // stage h0[t-1]; x-part MFMAs overlap the loads in flight
      const unsigned short* hprev = myring + (size_t)((t - 1) & (RING - 1)) * (32 * 512);
      u32x4 th[8];
#pragma unroll
      for (int k = 0; k < 8; ++k)
        th[k] = llc_load16((const char*)hprev + (size_t)(tid + k * 256) * 16);
#pragma unroll
      for (int kk = 0; kk < 8; ++kk) {
        acc0 = __builtin_amdgcn_mfma_f32_16x16x32_bf16(xf0[kk], wf[kk], acc0, 0, 0, 0);
        acc1 = __builtin_amdgcn_mfma_f32_16x16x32_bf16(xf1[kk], wf[kk], acc1, 0, 0, 0);
      }
      vmwait();
#pragma unroll
      for (int k = 0; k < 8; ++k) {
        int off = (tid + k * 256) * 16;
        *(u32x4*)((char*)hA + HSWZ(off)) = th[k];
      }
      __syncthreads();
#pragma unroll
      for (int kk = 0; kk < 16; ++kk) {
        int cb = (kk * 32 + kgrp * 8) * 2;
        bf16x8 a0 = *(const bf16x8*)((const char*)hA + HSWZ(l15 * 1024 + cb));
        bf16x8 a1 = *(const bf16x8*)((const char*)hA + HSWZ((16 + l15) * 1024 + cb));
        acc0 = __builtin_amdgcn_mfma_f32_16x16x32_bf16(a0, wf[8 + kk], acc0, 0, 0, 0);
        acc1 = __builtin_amdgcn_mfma_f32_16x16x32_bf16(a1, wf[8 + kk], acc1, 0, 0, 0);
      }
    } else {
      // ---- pre-poll phase: everything touching h0[t] (L0 runs ahead) ----
      // precheck: h0[t] published? (instant in steady state)
      spin_flags(s0, t + 1, s1, NEG_INF, sf, NEG_INF);
      const unsigned short* h0cur = h0r + (size_t)(t & (RING - 1)) * (32 * 512);
      u32x4 tx[8];
#pragma unroll
      for (int k = 0; k < 8; ++k)
        tx[k] = llc_load16((const char*)h0cur + (size_t)(tid + k * 256) * 16);
      vmwait();
#pragma unroll
      for (int k = 0; k < 8; ++k) {
        int off = (tid + k * 256) * 16;
        *(u32x4*)((char*)xA + HSWZ(off)) = tx[k];
      }
      __syncthreads();  // xA published
      // h0-part MFMAs: fully off the critical path (run during peer wait lead-in)
#pragma unroll
      for (int kk = 0; kk < 16; ++kk) {
        int cb = (kk * 32 + kgrp * 8) * 2;
        bf16x8 a0 = *(const bf16x8*)((const char*)xA + HSWZ(l15 * 1024 + cb));
        bf16x8 a1 = *(const bf16x8*)((const char*)xA + HSWZ((16 + l15) * 1024 + cb));
        acc0 = __builtin_amdgcn_mfma_f32_16x16x32_bf16(a0, wf[kk], acc0, 0, 0, 0);
        acc1 = __builtin_amdgcn_mfma_f32_16x16x32_bf16(a1, wf[kk], acc1, 0, 0, 0);
      }

      // ---- critical phase: peers' h1[t-1] (+ FC ring guard) ----
      spin_flags(s0, NEG_INF, s1, t, sf, t - (RING - 1));
      const unsigned short* hprev = myring + (size_t)((t - 1) & (RING - 1)) * (32 * 512);
      u32x4 th[8];
#pragma unroll
      for (int k = 0; k < 8; ++k)
        th[k] = llc_load16((const char*)hprev + (size_t)(tid + k * 256) * 16);
      vmwait();
#pragma unroll
      for (int k = 0; k < 8; ++k) {
        int off = (tid + k * 256) * 16;
        *(u32x4*)((char*)hA + HSWZ(off)) = th[k];
      }
      __syncthreads();
#pragma unroll
      for (int kk = 0; kk < 16; ++kk) {
        int cb = (kk * 32 + kgrp * 8) * 2;
        bf16x8 a0 = *(const bf16x8*)((const char*)hA + HSWZ(l15 * 1024 + cb));
        bf16x8 a1 = *(const bf16x8*)((const char*)hA + HSWZ((16 + l15) * 1024 + cb));
        acc0 = __builtin_amdgcn_mfma_f32_16x16x32_bf16(a0, wf[16 + kk], acc0, 0, 0, 0);
        acc1 = __builtin_amdgcn_mfma_f32_16x16x32_bf16(a1, wf[16 + kk], acc1, 0, 0, 0);
      }
    }

    // C/D: col(l15)=unit, row(kgrp*4+j)=batch.  gates[gate][batch][unit]
#pragma unroll
    for (int j = 0; j < 4; ++j) {
      gates[wave][kgrp * 4 + j][l15] = acc0[j];
      gates[wave][16 + kgrp * 4 + j][l15] = acc1[j];
    }
    __syncthreads();

    // ---- epilogue: 2 units x 1 batch per thread; c stays in registers ----
    unsigned short* hdst = myring + (size_t)(t & (RING - 1)) * (32 * 512);
    float i0 = sigm(gates[0][be][ue] + bi0);
    float ff0 = sigm(gates[1][be][ue] + bf0);
    float g0 = tanh_f(gates[2][be][ue] + bg0);
    float o0 = sigm(gates[3][be][ue] + bo0);
    cc0 = ff0 * cc0 + i0 * g0;
    float hv0 = o0 * tanh_f(cc0);
    float i1 = sigm(gates[0][be][ue + 1] + bi1);
    float ff1 = sigm(gates[1][be][ue + 1] + bf1);
    float g1 = tanh_f(gates[2][be][ue + 1] + bg1);
    float o1 = sigm(gates[3][be][ue + 1] + bo1);
    cc1 = ff1 * cc1 + i1 * g1;
    float hv1 = o1 * tanh_f(cc1);
    unsigned pv = (unsigned)f2b(hv0) | ((unsigned)f2b(hv1) << 16);
    llc_store4(hdst + (size_t)be * 512 + u0 + ue, pv);
    vmwait();            // this thread's h at LLC (drain BEFORE flag — r11 lesson)
    __syncthreads();     // all threads' h at LLC
    if (tid == 0) flag_st(myslot, t + 1);
  }
}

// ---------------- main persistent pipelined kernel ----------------
__global__ void __launch_bounds__(256) lstm_main(
    const unsigned short* __restrict__ xb,
    const unsigned short* __restrict__ wl0,
    const unsigned short* __restrict__ wl1,
    const unsigned short* __restrict__ wfcp,
    const float* __restrict__ b0,
    const float* __restrict__ b1,
    const float* __restrict__ bfc,
    unsigned short* __restrict__ h0r,
    unsigned short* __restrict__ h1r,
    int* flags,
    float* __restrict__ out) {
  __shared__ __align__(16) unsigned short hA[32 * 512];
  __shared__ __align__(16) unsigned short xA[32 * 512];
  __shared__ __align__(16) float gates[4][32][18];
  const int tid = threadIdx.x;
  const int wave = tid >> 6, lane = tid & 63, l15 = lane & 15, kgrp = lane >> 4;
  const int wid = blockIdx.x;
  int* s0 = flags;
  int* s1 = flags + NL0 * SLOT_STRIDE;
  int* sf = flags + (NL0 + NL1) * SLOT_STRIDE;

  if (wid < NL0) {
    lstm_path<1>(xb, wl0, b0, h0r, h1r, s0, s1, sf, wid, hA, xA, gates);
  } else if (wid < NL0 + NL1) {
    lstm_path<0>(xb, wl1, b1, h0r, h1r, s0, s1, sf, wid - NL0, hA, xA, gates);
  } else {
    const int fcw = wid - NL0 - NL1;  // 0..7
    const int mt = wave >> 1, ntile = wave & 1;
    const int orow = fcw * 32 + ntile * 16 + l15;
    bf16x8 wff[16];
#pragma unroll
    for (int kk = 0; kk < 16; ++kk)
      wff[kk] = *(const bf16x8*)(wfcp + (size_t)orow * 512 + kk * 32 + kgrp * 8);
    const float bb = bfc[orow];
    for (int t = 0; t < T_SEQ; ++t) {
      spin_flags(s0, NEG_INF, s1, t + 1, sf, NEG_INF);
      const unsigned short* hcur = h1r + (size_t)(t & (RING - 1)) * (32 * 512);
      u32x4 th[8];
#pragma unroll
      for (int k = 0; k < 8; ++k)
        th[k] = llc_load16((const char*)hcur + (size_t)(tid + k * 256) * 16);
      vmwait();
#pragma unroll
      for (int k = 0; k < 8; ++k) {
        int off = (tid + k * 256) * 16;
        *(u32x4*)((char*)hA + HSWZ(off)) = th[k];
      }
      __syncthreads();
      if (tid == 0) flag_st(sf + fcw * SLOT_STRIDE, t + 1);  // h1[t] consumed
      f32x4 acc = {0.f, 0.f, 0.f, 0.f};
#pragma unroll
      for (int kk = 0; kk < 16; ++kk) {
        int row = mt * 16 + l15;
        bf16x8 a = *(const bf16x8*)((const char*)hA + HSWZ(row * 1024 + (kk * 32 + kgrp * 8) * 2));
        acc = __builtin_amdgcn_mfma_f32_16x16x32_bf16(a, wff[kk], acc, 0, 0, 0);
      }
#pragma unroll
      for (int j = 0; j < 4; ++j) {
        int b = mt * 16 + kgrp * 4 + j;
        out[((size_t)b * T_SEQ + t) * 256 + orow] = acc[j] + bb;
      }
    }
  }
}

extern "C" void kernel_launch(void* const* d_in, const int* in_sizes, int n_in,
                              void* d_out, int out_size, void* d_ws, size_t ws_size,
                              hipStream_t stream) {
  const float* x    = (const float*)d_in[0];
  const float* wih0 = (const float*)d_in[1];
  const float* whh0 = (const float*)d_in[2];
  const float* b0   = (const float*)d_in[3];
  const float* wih1 = (const float*)d_in[4];
  const float* whh1 = (const float*)d_in[5];
  const float* b1   = (const float*)d_in[6];
  const float* wfc  = (const float*)d_in[7];
  const float* bfc  = (const float*)d_in[8];
  float* outp = (float*)d_out;

  char* ws = (char*)d_ws;
  size_t off = 0;
  unsigned short* wl0p = (unsigned short*)(ws + off); off += (size_t)2048 * 768 * 2;
  unsigned short* wl1p = (unsigned short*)(ws + off); off += (size_t)2048 * 1024 * 2;
  unsigned short* wfcp = (unsigned short*)(ws + off); off += (size_t)256 * 512 * 2;
  unsigned short* xbp  = (unsigned short*)(ws + off); off += (size_t)2048 * 32 * 256 * 2;
  unsigned short* h0rp = (unsigned short*)(ws + off); off += (size_t)RING * 32 * 512 * 2;
  unsigned short* h1rp = (unsigned short*)(ws + off); off += (size_t)RING * 32 * 512 * 2;
  int* flagsp = (int*)(ws + off); off += (size_t)NWG * SLOT_STRIDE * sizeof(int);

  lstm_prologue<<<dim3(1024), dim3(256), 0, stream>>>(
      x, wih0, whh0, wih1, whh1, wfc, wl0p, wl1p, wfcp, xbp, h0rp, h1rp, flagsp);

  lstm_main<<<dim3(NWG), dim3(256), 0, stream>>>(
      xbp, wl0p, wl1p, wfcp, b0, b1, bfc, h0rp, h1rp, flagsp, outp);
}